// Round 11
// baseline (131.528 us; speedup 1.0000x reference)
//
#include <hip/hip_runtime.h>

#define B_    4
#define TE_   256
#define TD_   256
#define DE_   512
#define K_    512

typedef __attribute__((ext_vector_type(8))) short bf16x8;
typedef __attribute__((ext_vector_type(4))) float f32x4;

// 2*log2(e): folded into Ua/Wa so the sigmoid arg is exp2-ready.
#define C1F 2.8853900817779268f

__device__ __forceinline__ ushort f2bf(float x) {
  uint u = __float_as_uint(x);
  return (ushort)((u + 0x7fffu + ((u >> 16) & 1u)) >> 16);
}
__device__ __forceinline__ float bf2f(ushort h) {
  return __uint_as_float(((uint)h) << 16);
}
__device__ __forceinline__ float exp2_fast(float x) {
  float r;
  asm("v_exp_f32 %0, %1" : "=v"(r) : "v"(x));
  return r;
}

// ---- enc/dec [1024,512] f32 -> hi/lo bf16 (row-major) ----
__global__ __launch_bounds__(256) void conv_hilo(
    const float* __restrict__ enc, const float* __restrict__ dec,
    ushort* __restrict__ ehi, ushort* __restrict__ elo,
    ushort* __restrict__ dhi, ushort* __restrict__ dlo) {
  const float* in = blockIdx.y ? dec : enc;
  ushort* hi = blockIdx.y ? dhi : ehi;
  ushort* lo = blockIdx.y ? dlo : elo;
  int i = (blockIdx.x * 256 + threadIdx.x) * 4;
  float4 v = *(const float4*)&in[i];
  ushort4 h, l;
  h.x = f2bf(v.x); l.x = f2bf(v.x - bf2f(h.x));
  h.y = f2bf(v.y); l.y = f2bf(v.y - bf2f(h.y));
  h.z = f2bf(v.z); l.z = f2bf(v.z - bf2f(h.z));
  h.w = f2bf(v.w); l.w = f2bf(v.w - bf2f(h.w));
  *(ushort4*)&hi[i] = h;
  *(ushort4*)&lo[i] = l;
}

// ---- C1*Ua, C1*Wa [K,N] -> n-major [N,K] hi/lo bf16 ----
__global__ __launch_bounds__(256) void conv_bt(
    const float* __restrict__ Ua, const float* __restrict__ Wa,
    ushort* __restrict__ uhi, ushort* __restrict__ ulo,
    ushort* __restrict__ whi, ushort* __restrict__ wlo) {
  const float* in = blockIdx.z ? Wa : Ua;
  ushort* thi = blockIdx.z ? whi : uhi;
  ushort* tlo = blockIdx.z ? wlo : ulo;
  __shared__ float tile[64][65];
  int k0 = blockIdx.y * 64, n0 = blockIdx.x * 64;
  int tid = threadIdx.x;
#pragma unroll
  for (int i = 0; i < 16; ++i) {
    int idx = tid + i * 256;
    int r = idx >> 6, c = idx & 63;
    tile[r][c] = in[(size_t)(k0 + r) * 512 + n0 + c];
  }
  __syncthreads();
#pragma unroll
  for (int i = 0; i < 16; ++i) {
    int idx = tid + i * 256;
    int rn = idx >> 6, ck = idx & 63;
    float x = tile[ck][rn] * C1F;
    ushort h = f2bf(x);
    size_t o = (size_t)(n0 + rn) * 512 + k0 + ck;
    thi[o] = h;
    tlo[o] = f2bf(x - bf2f(h));
  }
}

// ---- LDS-free split-bf16 MFMA GEMM: 1 wave/block, 32x32 tile ----
// All operands are row-major-[row][k]; MFMA A/B frags are row-gathers,
// loaded straight from global (L2-resident). No LDS, no barriers.
// z=0: UhT[d][b*256+e] = (C1*Ua)^T @ enc^T   (A=uhi, B=ehi)
// z=1: Ws[b*256+t][d]  = dec @ (C1*Wa)       (A=dhi, B=whi)
// 3-term split: hh + hl + lh.
__global__ __launch_bounds__(64) void gemm_mfma(
    const ushort* __restrict__ ehi, const ushort* __restrict__ elo,
    const ushort* __restrict__ dhi, const ushort* __restrict__ dlo,
    const ushort* __restrict__ uhi, const ushort* __restrict__ ulo,
    const ushort* __restrict__ whi, const ushort* __restrict__ wlo,
    float* __restrict__ UhT, float* __restrict__ Ws) {
  const ushort *Ahi, *Alo, *Bhi, *Blo;
  int bid = blockIdx.x, bm, bn;
  if (blockIdx.z == 0) {
    Ahi = uhi; Alo = ulo; Bhi = ehi; Blo = elo;   // M=512(d), N=1024(b,e)
    bn = (bid & 31) * 32; bm = (bid >> 5) * 32;
  } else {
    Ahi = dhi; Alo = dlo; Bhi = whi; Blo = wlo;   // M=1024(b,t), N=512(d)
    bn = (bid & 15) * 32; bm = (bid >> 4) * 32;
  }
  int lane = threadIdx.x;
  int frow = lane & 15, fk = (lane >> 4) * 8;     // frag row, 16B k-chunk
  size_t ao = (size_t)(bm + frow) * K_ + fk;
  size_t bo = (size_t)(bn + frow) * K_ + fk;
  const ushort* pah0 = Ahi + ao; const ushort* pah1 = pah0 + 16 * K_;
  const ushort* pal0 = Alo + ao; const ushort* pal1 = pal0 + 16 * K_;
  const ushort* pbh0 = Bhi + bo; const ushort* pbh1 = pbh0 + 16 * K_;
  const ushort* pbl0 = Blo + bo; const ushort* pbl1 = pbl0 + 16 * K_;
  f32x4 a00 = {}, a01 = {}, a10 = {}, a11 = {};
#pragma unroll 2
  for (int k0 = 0; k0 < K_; k0 += 32) {
    bf16x8 ah0 = *(const bf16x8*)&pah0[k0], ah1 = *(const bf16x8*)&pah1[k0];
    bf16x8 al0 = *(const bf16x8*)&pal0[k0], al1 = *(const bf16x8*)&pal1[k0];
    bf16x8 bh0 = *(const bf16x8*)&pbh0[k0], bh1 = *(const bf16x8*)&pbh1[k0];
    bf16x8 bl0 = *(const bf16x8*)&pbl0[k0], bl1 = *(const bf16x8*)&pbl1[k0];
    a00 = __builtin_amdgcn_mfma_f32_16x16x32_bf16(ah0, bh0, a00, 0, 0, 0);
    a01 = __builtin_amdgcn_mfma_f32_16x16x32_bf16(ah0, bh1, a01, 0, 0, 0);
    a10 = __builtin_amdgcn_mfma_f32_16x16x32_bf16(ah1, bh0, a10, 0, 0, 0);
    a11 = __builtin_amdgcn_mfma_f32_16x16x32_bf16(ah1, bh1, a11, 0, 0, 0);
    a00 = __builtin_amdgcn_mfma_f32_16x16x32_bf16(ah0, bl0, a00, 0, 0, 0);
    a01 = __builtin_amdgcn_mfma_f32_16x16x32_bf16(ah0, bl1, a01, 0, 0, 0);
    a10 = __builtin_amdgcn_mfma_f32_16x16x32_bf16(ah1, bl0, a10, 0, 0, 0);
    a11 = __builtin_amdgcn_mfma_f32_16x16x32_bf16(ah1, bl1, a11, 0, 0, 0);
    a00 = __builtin_amdgcn_mfma_f32_16x16x32_bf16(al0, bh0, a00, 0, 0, 0);
    a01 = __builtin_amdgcn_mfma_f32_16x16x32_bf16(al0, bh1, a01, 0, 0, 0);
    a10 = __builtin_amdgcn_mfma_f32_16x16x32_bf16(al1, bh0, a10, 0, 0, 0);
    a11 = __builtin_amdgcn_mfma_f32_16x16x32_bf16(al1, bh1, a11, 0, 0, 0);
  }
  // C/D: col=lane&15, row=(lane>>4)*4+r  [verified empirically r6]
  int crow = (lane >> 4) * 4, ccol = lane & 15;
#pragma unroll
  for (int i = 0; i < 2; ++i)
#pragma unroll
    for (int j = 0; j < 2; ++j) {
      const f32x4& acc = i == 0 ? (j == 0 ? a00 : a01) : (j == 0 ? a10 : a11);
      int m0 = bm + i * 16 + crow;
      int n0 = bn + j * 16 + ccol;
      if (blockIdx.z == 0) {
        float* cb = UhT + (size_t)(n0 >> 8) * 131072 + (size_t)m0 * 256 + (n0 & 255);
#pragma unroll
        for (int r = 0; r < 4; ++r) cb[(size_t)r * 256] = acc[r];
      } else {
        float* cb = Ws + (size_t)m0 * 512 + n0;
#pragma unroll
        for (int r = 0; r < 4; ++r) cb[(size_t)r * 512] = acc[r];
      }
    }
}

// ---- fused energies + softmax + context ----
// 512 blocks x 512 thr. Phase 1: thread owns e-quad (float4 of UhT row),
// d-range split 8x within wave (lane = dg*8 + qlow); 8 accs; butterfly
// shfl_xor(8/16/32) reduce. Energy: e~ = sum mv[d]*rcp(1+2^(u'+w')),
// mv = -2*Va (softmax-invariant shift).
__global__ __launch_bounds__(512) void fused_attn(
    const float* __restrict__ enc, const float* __restrict__ UhT,
    const float* __restrict__ Ws, const float* __restrict__ Va,
    float* __restrict__ out_ctx, float* __restrict__ out_attn) {
  int bt = blockIdx.x;
  int b  = bt >> 7;
  int t0 = (bt & 127) * 2;
  __shared__ float ws0_s[520], ws1_s[520], mv_s[520];   // pad: idx d+(d>>6)
  __shared__ float e_s[2][TE_];
  __shared__ float att2[TE_ * 2];
  __shared__ float redm[2][4], reds[2][4];
  int tid = threadIdx.x, lane = tid & 63, w = tid >> 6;

  const float* wsr = Ws + (size_t)(b * TD_ + t0) * DE_;
  int pd0 = tid + (tid >> 6);
  ws0_s[pd0] = wsr[tid];
  ws1_s[pd0] = wsr[DE_ + tid];
  mv_s[pd0]  = -2.0f * Va[tid];
  __syncthreads();

  // ---- phase 1 ----
  int dg = lane >> 3, qlow = lane & 7;
  int q = w * 8 + qlow;                       // e-quad: e = q*4..q*4+3
  const float* up = UhT + (size_t)b * 131072 + (size_t)dg * 64 * 256 + q * 4;
  int pbase = dg * 65;                        // padded LDS base for d=dg*64
  float a0[4] = {}, a1[4] = {};
#pragma unroll 8
  for (int i = 0; i < 64; ++i) {
    float4 u4 = *(const float4*)&up[(size_t)i * 256];
    float w0 = ws0_s[pbase + i];
    float w1 = ws1_s[pbase + i];
    float mv = mv_s[pbase + i];
#pragma unroll
    for (int j = 0; j < 4; ++j) {
      float u = j == 0 ? u4.x : j == 1 ? u4.y : j == 2 ? u4.z : u4.w;
      a0[j] = fmaf(mv, __builtin_amdgcn_rcpf(1.0f + exp2_fast(u + w0)), a0[j]);
      a1[j] = fmaf(mv, __builtin_amdgcn_rcpf(1.0f + exp2_fast(u + w1)), a1[j]);
    }
  }
#pragma unroll
  for (int j = 0; j < 4; ++j) {
#pragma unroll
    for (int off = 8; off <= 32; off <<= 1) {
      a0[j] += __shfl_xor(a0[j], off);
      a1[j] += __shfl_xor(a1[j], off);
    }
  }
  if (dg == 0) {                              // lanes 0..7 hold quad sums
    float4 v0 = make_float4(a0[0], a0[1], a0[2], a0[3]);
    float4 v1 = make_float4(a1[0], a1[1], a1[2], a1[3]);
    *(float4*)&e_s[0][q * 4] = v0;
    *(float4*)&e_s[1][q * 4] = v1;
  }
  __syncthreads();

  // ---- phase 2: softmax (threads 0-255 -> t0, 256-511 -> t1) ----
  int t = tid >> 8, col = tid & 255;
  float x = e_s[t][col];
  float m = x;
#pragma unroll
  for (int off = 32; off; off >>= 1) m = fmaxf(m, __shfl_xor(m, off));
  if (lane == 0) redm[t][w & 3] = m;
  __syncthreads();
  m = fmaxf(fmaxf(redm[t][0], redm[t][1]), fmaxf(redm[t][2], redm[t][3]));
  float p = __expf(x - m);
  float s = p;
#pragma unroll
  for (int off = 32; off; off >>= 1) s += __shfl_xor(s, off);
  if (lane == 0) reds[t][w & 3] = s;
  __syncthreads();
  s = reds[t][0] + reds[t][1] + reds[t][2] + reds[t][3];
  float a = p * __builtin_amdgcn_rcpf(s);
  att2[col * 2 + t] = a;
  out_attn[(size_t)(b * TD_ + t0 + t) * TE_ + col] = a;
  __syncthreads();

  // ---- phase 3: context (thread owns column d = tid, both t rows) ----
  const float* enc_b = enc + (size_t)b * TE_ * DE_;
  float c0 = 0.f, c1 = 0.f;
#pragma unroll 4
  for (int ee = 0; ee < TE_; ++ee) {
    float2 av = *(const float2*)&att2[ee * 2];
    float xv = enc_b[(size_t)ee * DE_ + tid];
    c0 = fmaf(av.x, xv, c0);
    c1 = fmaf(av.y, xv, c1);
  }
  float* ctx0 = out_ctx + (size_t)(b * TD_ + t0) * DE_;
  ctx0[tid]       = c0;
  ctx0[DE_ + tid] = c1;
}

extern "C" void kernel_launch(void* const* d_in, const int* in_sizes, int n_in,
                              void* d_out, int out_size, void* d_ws, size_t ws_size,
                              hipStream_t stream) {
  const float* enc = (const float*)d_in[0];
  const float* dec = (const float*)d_in[1];
  const float* Ua  = (const float*)d_in[2];
  const float* Wa  = (const float*)d_in[3];
  const float* Va  = (const float*)d_in[4];

  float* out_ctx  = (float*)d_out;                     // [B,TD,DE]
  float* out_attn = out_ctx + (size_t)B_ * TD_ * DE_;  // [B,TD,TE]

  char* wsp = (char*)d_ws;
  float* UhT = (float*)wsp;             wsp += (size_t)B_ * DE_ * TE_ * 4;  // [B][512 d][256 e]
  float* Wsm = (float*)wsp;             wsp += (size_t)B_ * TD_ * DE_ * 4;  // [B*256 t][512 d]
  ushort* ehi = (ushort*)wsp;           wsp += (size_t)B_ * TE_ * DE_ * 2;
  ushort* elo = (ushort*)wsp;           wsp += (size_t)B_ * TE_ * DE_ * 2;
  ushort* dhi = (ushort*)wsp;           wsp += (size_t)B_ * TD_ * DE_ * 2;
  ushort* dlo = (ushort*)wsp;           wsp += (size_t)B_ * TD_ * DE_ * 2;
  ushort* uhi = (ushort*)wsp;           wsp += (size_t)K_ * DE_ * 2;
  ushort* ulo = (ushort*)wsp;           wsp += (size_t)K_ * DE_ * 2;
  ushort* whi = (ushort*)wsp;           wsp += (size_t)K_ * DE_ * 2;
  ushort* wlo = (ushort*)wsp;           wsp += (size_t)K_ * DE_ * 2;

  conv_hilo<<<dim3(512, 2), 256, 0, stream>>>(enc, dec, ehi, elo, dhi, dlo);
  conv_bt<<<dim3(8, 8, 2), 256, 0, stream>>>(Ua, Wa, uhi, ulo, whi, wlo);
  gemm_mfma<<<dim3(512, 1, 2), 64, 0, stream>>>(
      ehi, elo, dhi, dlo, uhi, ulo, whi, wlo, UhT, Wsm);
  fused_attn<<<512, 512, 0, stream>>>(enc, UhT, Wsm, Va, out_ctx, out_attn);
}